// Round 1
// baseline (450.755 us; speedup 1.0000x reference)
//
#include <hip/hip_runtime.h>

// Deformable 2x bilinear upsample.
// input:  (B=8, C=128, H=128, W=128) fp32
// offset_x/offset_y: (B, 1, Ho=256, Wo=256) fp32
// out:    (B, C, Ho, Wo) fp32
//
// Coordinates depend only on (b,ho,wo): compute weights/indices once,
// loop over a channel group. Memory-bound: 256 MiB store + ~100 MiB load.

constexpr int B  = 8;
constexpr int C  = 128;
constexpr int H  = 128;
constexpr int W  = 128;
constexpr int KH = 2;
constexpr int KW = 2;
constexpr int Ho = H * KH;   // 256
constexpr int Wo = W * KW;   // 256
constexpr int HW = H * W;    // 16384
constexpr int CG  = 4;       // channel groups (grid.z)
constexpr int CPG = C / CG;  // 32 channels per thread

__global__ __launch_bounds__(256) void deform_upsample_kernel(
    const float* __restrict__ in,
    const float* __restrict__ offx,
    const float* __restrict__ offy,
    float* __restrict__ out)
{
    const int t   = threadIdx.x;
    const int wo4 = (t & 63) * 4;                 // 64 threads cover Wo=256, 4 each
    const int ho  = blockIdx.x * 4 + (t >> 6);    // 4 rows per block
    const int b   = blockIdx.y;
    const int c0  = blockIdx.z * CPG;

    // Offsets: shape (B,1,Ho,Wo)
    const int sbase = (b * Ho + ho) * Wo + wo4;
    const float4 ox4 = *reinterpret_cast<const float4*>(offx + sbase);
    const float4 oy4 = *reinterpret_cast<const float4*>(offy + sbase);

    const float oxv[4] = {ox4.x, ox4.y, ox4.z, ox4.w};
    const float oyv[4] = {oy4.x, oy4.y, oy4.z, oy4.w};

    int   idx[16];   // [pos*4 + corner], plane-relative
    float wgt[16];   // validity-masked bilinear weights

    const float base_y = (float)ho * 0.5f;

#pragma unroll
    for (int j = 0; j < 4; ++j) {
        const float y = base_y + oyv[j];
        const float x = (float)(wo4 + j) * 0.5f + oxv[j];
        const float y0f = floorf(y);
        const float x0f = floorf(x);
        const float wy = y - y0f;
        const float wx = x - x0f;
        const int y0 = (int)y0f;
        const int x0 = (int)x0f;
        const int y1 = y0 + 1;
        const int x1 = x0 + 1;

        const bool vy0 = ((unsigned)y0 < (unsigned)H);
        const bool vy1 = ((unsigned)y1 < (unsigned)H);
        const bool vx0 = ((unsigned)x0 < (unsigned)W);
        const bool vx1 = ((unsigned)x1 < (unsigned)W);

        const int yc0 = min(max(y0, 0), H - 1);
        const int yc1 = min(max(y1, 0), H - 1);
        const int xc0 = min(max(x0, 0), W - 1);
        const int xc1 = min(max(x1, 0), W - 1);

        idx[j * 4 + 0] = yc0 * W + xc0;
        idx[j * 4 + 1] = yc0 * W + xc1;
        idx[j * 4 + 2] = yc1 * W + xc0;
        idx[j * 4 + 3] = yc1 * W + xc1;

        const float omwy = 1.0f - wy;
        const float omwx = 1.0f - wx;
        wgt[j * 4 + 0] = (vy0 && vx0) ? (omwy * omwx) : 0.0f;
        wgt[j * 4 + 1] = (vy0 && vx1) ? (omwy * wx)   : 0.0f;
        wgt[j * 4 + 2] = (vy1 && vx0) ? (wy   * omwx) : 0.0f;
        wgt[j * 4 + 3] = (vy1 && vx1) ? (wy   * wx)   : 0.0f;
    }

    const float* ip = in  + (size_t)(b * C + c0) * HW;
    float*       op = out + ((size_t)(b * C + c0) * Ho + ho) * Wo + wo4;

#pragma unroll 2
    for (int c = 0; c < CPG; ++c) {
        float r[4];
#pragma unroll
        for (int j = 0; j < 4; ++j) {
            float acc;
            acc  = wgt[j * 4 + 0] * ip[idx[j * 4 + 0]];
            acc  = fmaf(wgt[j * 4 + 1], ip[idx[j * 4 + 1]], acc);
            acc  = fmaf(wgt[j * 4 + 2], ip[idx[j * 4 + 2]], acc);
            acc  = fmaf(wgt[j * 4 + 3], ip[idx[j * 4 + 3]], acc);
            r[j] = acc;
        }
        float4 rv = make_float4(r[0], r[1], r[2], r[3]);
        *reinterpret_cast<float4*>(op) = rv;
        ip += HW;
        op += Ho * Wo;
    }
}

extern "C" void kernel_launch(void* const* d_in, const int* in_sizes, int n_in,
                              void* d_out, int out_size, void* d_ws, size_t ws_size,
                              hipStream_t stream) {
    const float* in   = (const float*)d_in[0];
    const float* offx = (const float*)d_in[1];
    const float* offy = (const float*)d_in[2];
    float* out = (float*)d_out;

    dim3 grid(Ho / 4, B, CG);   // 64 x 8 x 4 = 2048 blocks
    dim3 block(256);
    deform_upsample_kernel<<<grid, block, 0, stream>>>(in, offx, offy, out);
}